// Round 7
// baseline (724.350 us; speedup 1.0000x reference)
//
#include <hip/hip_runtime.h>
#include <hip/hip_fp16.h>

#define Hn 128
#define Wn 128
#define HWn 16384
#define Cn 64
#define Bn 8
#define NTOT (Bn*Cn*HWn)   /* 8388608 */
#define NPIX (Bn*HWn)      /* 131072  */
#define DTc 0.3f
#define EPSc 1e-5f

__device__ __forceinline__ float sigm(float t){ return 1.0f/(1.0f+__expf(-t)); }

// ---------------- F = force + 0.2*illum (fp16) + fused oscillator step 0 ----------------
// x0=v0=0  =>  accel0 = F, v1 = 0.3*F, x1 = 0.09*F
__global__ void fuseF0(const float4* __restrict__ force, const float4* __restrict__ illum,
                       __half* __restrict__ F, __half* __restrict__ XA, __half* __restrict__ V)
{
    int i = blockIdx.x * blockDim.x + threadIdx.x;      // NTOT/4 threads
    float4 f = force[i], il = illum[i];
    float a0 = f.x + 0.2f*il.x, a1 = f.y + 0.2f*il.y;
    float a2 = f.z + 0.2f*il.z, a3 = f.w + 0.2f*il.w;
    uint2 pf, px, pv;
    __half2 h;
    h = __floats2half2_rn(a0, a1);            pf.x = *(unsigned int*)&h;
    h = __floats2half2_rn(a2, a3);            pf.y = *(unsigned int*)&h;
    h = __floats2half2_rn(0.09f*a0, 0.09f*a1); px.x = *(unsigned int*)&h;
    h = __floats2half2_rn(0.09f*a2, 0.09f*a3); px.y = *(unsigned int*)&h;
    h = __floats2half2_rn(0.3f*a0, 0.3f*a1);   pv.x = *(unsigned int*)&h;
    h = __floats2half2_rn(0.3f*a2, 0.3f*a3);   pv.y = *(unsigned int*)&h;
    *reinterpret_cast<uint2*>(F  + 4*(size_t)i) = pf;
    *reinterpret_cast<uint2*>(XA + 4*(size_t)i) = px;
    *reinterpret_cast<uint2*>(V  + 4*(size_t)i) = pv;
}

// ---------------- prep: style constant + weight transposes ----------------
__global__ void prep(const float* __restrict__ style, const float* __restrict__ w1,
                     const float* __restrict__ b1, const float* __restrict__ pw,
                     const float* __restrict__ pw1, const float* __restrict__ pw2,
                     float* __restrict__ w1T, float* __restrict__ c1,
                     float* __restrict__ pwT, float* __restrict__ pw1T,
                     float* __restrict__ pw2T)
{
    int t = threadIdx.x;
    if (t < 32) {
        float s = b1[t];
        for (int k = 0; k < 64; k++) s += w1[t*128 + 64 + k] * style[k];
        c1[t] = s;
    }
    for (int i = t; i < 2048; i += 256) { int c = i >> 5, j = i & 31; w1T[i] = w1[j*128 + c]; }
    for (int i = t; i < 4096; i += 256) {
        int c = i >> 6, k = i & 63;
        pwT[i]  = pw[k*64 + c];
        pw1T[i] = pw1[k*64 + c];
        pw2T[i] = pw2[k*64 + c];
    }
}

// ---------------- hyper encoder, 2-way split: y=0 -> AB(half2), y=1 -> GB(half2) --------
__global__ void hyper2(const __half* __restrict__ F,
                       const float* __restrict__ w1T, const float* __restrict__ c1,
                       const float* __restrict__ w2, const float* __restrict__ b2,
                       const float* __restrict__ w3, const float* __restrict__ b3,
                       __half2* __restrict__ AB, __half2* __restrict__ GB)
{
    int p = blockIdx.x * blockDim.x + threadIdx.x;
    int b  = p >> 14;
    int sp = p & (HWn - 1);
    int base = b * Cn * HWn + sp;

    float u1[32];
#pragma unroll
    for (int j = 0; j < 32; j++) u1[j] = c1[j];
#pragma unroll 4
    for (int c = 0; c < 64; c++) {
        float fc = __half2float(F[base + c*HWn]);
        const float* __restrict__ wr = w1T + c*32;
#pragma unroll
        for (int j = 0; j < 32; j++) u1[j] += wr[j] * fc;
    }
#pragma unroll
    for (int j = 0; j < 32; j++) { float v = u1[j]; u1[j] = v > 0.f ? v : 0.2f*v; }

    float u2[32];
#pragma unroll
    for (int i = 0; i < 32; i++) {
        float s = b2[i];
#pragma unroll
        for (int j = 0; j < 32; j++) s += w2[i*32 + j] * u1[j];
        u2[i] = s > 0.f ? s : 0.2f*s;
    }

    if (blockIdx.y == 0) {
        for (int j = 0; j < 64; j++) {
            const float* __restrict__ r0 = w3 + j*32;
            const float* __restrict__ r1 = w3 + (64 + j)*32;
            float pwv = b3[j], pz = b3[64 + j];
#pragma unroll
            for (int i = 0; i < 32; i++) { pwv += r0[i]*u2[i]; pz += r1[i]*u2[i]; }
            float om = 2.0f * sigm(pwv);
            float ze = sigm(pz);
            AB[base + j*HWn] = __floats2half2_rn(2.0f * ze * om, om * om);
        }
    } else {
        for (int j = 0; j < 64; j++) {
            const float* __restrict__ r2 = w3 + (128 + j)*32;
            const float* __restrict__ r3 = w3 + (192 + j)*32;
            float pg = b3[128 + j], pb = b3[192 + j];
#pragma unroll
            for (int i = 0; i < 32; i++) { pg += r2[i]*u2[i]; pb += r3[i]*u2[i]; }
            GB[base + j*HWn] = __floats2half2_rn(2.0f * sigm(pg), tanhf(pb));
        }
    }
}

// ---------------- oscillator step, 2 pixels/thread, 16-channel groups, packed loads ------
// Thread q handles pixels p0=2q, p0+1 (same row). All X/V/F loads are dword (2 fp16).
template <bool LAST>
__global__ __launch_bounds__(256, 4)
void osc2(const __half* __restrict__ Xin, __half* __restrict__ Xout,
          __half* __restrict__ V, const __half* __restrict__ F,
          const __half2* __restrict__ AB, const float* __restrict__ dwk,
          const float* __restrict__ pwT, float* __restrict__ Xf, float* __restrict__ Vf)
{
    int q  = blockIdx.x * blockDim.x + threadIdx.x;    // pixel-pair id
    int c0 = blockIdx.y << 4;                          // channel group (uniform)
    int p0 = q << 1;
    int b  = p0 >> 14;
    int sp = p0 & (HWn - 1);
    int y = sp >> 7, x0 = sp & 127;                    // x0 even
    int base = b * Cn * HWn + sp;

    int   yo[3] = { y > 0 ? -Wn : 0, 0, y < Hn-1 ? Wn : 0 };
    float my[3] = { y > 0 ? 1.f : 0.f, 1.f, y < Hn-1 ? 1.f : 0.f };
    float wl = x0 > 0   ? 1.f : 0.f;                   // pixel0 left tap
    float wr = x0 < 126 ? 1.f : 0.f;                   // pixel1 right tap

    // pointwise coupling over all 64 input channels (packed 2-pixel loads)
    float acc0[16], acc1[16];
#pragma unroll
    for (int k = 0; k < 16; k++) { acc0[k] = 0.f; acc1[k] = 0.f; }
#pragma unroll 8
    for (int c = 0; c < 64; c++) {
        unsigned int d = *reinterpret_cast<const unsigned int*>(Xin + base + c*HWn);
        float2 xc = __half22float2(*(__half2*)&d);
        const float* __restrict__ wrp = pwT + c*64 + c0;
#pragma unroll
        for (int k = 0; k < 16; k++) { acc0[k] += wrp[k]*xc.x; acc1[k] += wrp[k]*xc.y; }
    }

#pragma unroll
    for (int cc = 0; cc < 16; cc++) {
        int c = c0 + cc;
        int cb = base + c*HWn;
        // 3 rows x (2 center + left + right) taps
        float h0[3], h1[3], lf[3], rt[3];
#pragma unroll
        for (int r = 0; r < 3; r++) {
            const __half* __restrict__ rp = Xin + cb + yo[r];
            unsigned int d = *reinterpret_cast<const unsigned int*>(rp);
            float2 hv = __half22float2(*(__half2*)&d);
            h0[r] = hv.x; h1[r] = hv.y;
            lf[r] = __half2float(rp[-1]);   // masked by wl (OOB-by-1 lands in valid ws)
            rt[r] = __half2float(rp[2]);    // masked by wr
        }
        float dws0 = 0.f, dws1 = 0.f;
#pragma unroll
        for (int r = 0; r < 3; r++) {
            float k0 = dwk[c*9 + r*3 + 0] * my[r];
            float k1 = dwk[c*9 + r*3 + 1] * my[r];
            float k2 = dwk[c*9 + r*3 + 2] * my[r];
            dws0 += k0 * (wl * lf[r]) + k1 * h0[r] + k2 * h1[r];
            dws1 += k0 * h0[r] + k1 * h1[r] + k2 * (wr * rt[r]);
        }
        float xc0 = h0[1], xc1 = h1[1];
        unsigned int vd = *reinterpret_cast<const unsigned int*>(V + cb);
        float2 vv = __half22float2(*(__half2*)&vd);
        unsigned int fd = *reinterpret_cast<const unsigned int*>(F + cb);
        float2 ff = __half22float2(*(__half2*)&fd);
        uint2 abd = *reinterpret_cast<const uint2*>(AB + cb);
        float2 ab0 = __half22float2(*(__half2*)&abd.x);
        float2 ab1 = __half22float2(*(__half2*)&abd.y);
        float accel0 = ff.x + acc0[cc] + dws0 - ab0.x*vv.x - ab0.y*xc0;
        float accel1 = ff.y + acc1[cc] + dws1 - ab1.x*vv.y - ab1.y*xc1;
        float v0 = vv.x + accel0 * DTc;
        float v1 = vv.y + accel1 * DTc;
        float xn0 = xc0 + v0 * DTc;
        float xn1 = xc1 + v1 * DTc;
        if constexpr (!LAST) {
            __half2 hx = __floats2half2_rn(xn0, xn1);
            __half2 hv2 = __floats2half2_rn(v0, v1);
            *reinterpret_cast<unsigned int*>(Xout + cb) = *(unsigned int*)&hx;
            *reinterpret_cast<unsigned int*>(V + cb)    = *(unsigned int*)&hv2;
        } else {
            *reinterpret_cast<float2*>(Xf + cb) = make_float2(xn0, xn1);
            *reinterpret_cast<float2*>(Vf + cb) = make_float2(v0, v1);
        }
    }
}

// ---------------- instance norm stats ----------------
__global__ void inorm_stats(const __half* __restrict__ F, const float* __restrict__ X,
                            float* __restrict__ mu, float* __restrict__ rs)
{
    int bc = blockIdx.x;             // 0..511
    int base = bc * HWn;
    const __half2* __restrict__ F2 = (const __half2*)(F + base);
    const float4*  __restrict__ X4 = (const float4*)(X + base);
    float s = 0.f, s2 = 0.f;
    for (int i = threadIdx.x; i < HWn/4; i += blockDim.x) {
        float4 xv = X4[i];
        float2 f0 = __half22float2(F2[2*i]);
        float2 f1 = __half22float2(F2[2*i+1]);
        float v0 = f0.x + xv.x, v1 = f0.y + xv.y, v2 = f1.x + xv.z, v3 = f1.y + xv.w;
        s += (v0 + v1) + (v2 + v3);
        s2 += (v0*v0 + v1*v1) + (v2*v2 + v3*v3);
    }
#pragma unroll
    for (int o = 32; o > 0; o >>= 1) { s += __shfl_down(s, o); s2 += __shfl_down(s2, o); }
    __shared__ float sh[16];
    int w = threadIdx.x >> 6, l = threadIdx.x & 63;
    if (l == 0) { sh[w] = s; sh[8 + w] = s2; }
    __syncthreads();
    if (threadIdx.x == 0) {
        float S = 0.f, S2 = 0.f;
        for (int i = 0; i < 4; i++) { S += sh[i]; S2 += sh[8 + i]; }
        float m = S / (float)HWn;
        float var = S2 / (float)HWn - m*m;
        mu[bc] = m;
        rs[bc] = rsqrtf(var + EPSc);
    }
}

// ---------------- instance norm apply + style modulation -> out_pre (fp16) ----------------
__global__ void modulate(const __half* __restrict__ F, const float4* __restrict__ X4,
                         const uint4* __restrict__ GBu, const float* __restrict__ mu,
                         const float* __restrict__ rs, __half* __restrict__ outp)
{
    int e4 = blockIdx.x * blockDim.x + threadIdx.x;   // NTOT/4 threads
    int bc = e4 >> 12;                                // (e4*4) >> 14
    float m = mu[bc], r = rs[bc];
    uint2 fu = *reinterpret_cast<const uint2*>(F + 4*(size_t)e4);
    float2 f0 = __half22float2(*(__half2*)&fu.x);
    float2 f1 = __half22float2(*(__half2*)&fu.y);
    float4 xv = X4[e4];
    uint4 gb = GBu[e4];
    float2 g0 = __half22float2(*(__half2*)&gb.x);
    float2 g1 = __half22float2(*(__half2*)&gb.y);
    float2 g2 = __half22float2(*(__half2*)&gb.z);
    float2 g3 = __half22float2(*(__half2*)&gb.w);
    float o0 = g0.x * ((f0.x + xv.x - m) * r) + g0.y;
    float o1 = g1.x * ((f0.y + xv.y - m) * r) + g1.y;
    float o2 = g2.x * ((f1.x + xv.z - m) * r) + g2.y;
    float o3 = g3.x * ((f1.y + xv.w - m) * r) + g3.y;
    __half2 h01 = __floats2half2_rn(o0, o1);
    __half2 h23 = __floats2half2_rn(o2, o3);
    uint2 pack; pack.x = *(unsigned int*)&h01; pack.y = *(unsigned int*)&h23;
    *reinterpret_cast<uint2*>(outp + 4*(size_t)e4) = pack;
}

// ---------------- refine: LDS-staged weights (fp16), 128 px x 4 ch-groups / block -------
__global__ __launch_bounds__(512)
void refine(const __half* __restrict__ outp,
            const float* __restrict__ rdwk, const float* __restrict__ rdwb,
            const float* __restrict__ pw1T, const float* __restrict__ pb1,
            const float* __restrict__ pw2T, const float* __restrict__ pb2,
            const float* __restrict__ ls, float* __restrict__ out)
{
    __shared__ __half rv_s[64][128];
    __shared__ __half act_s[64][128];
    __shared__ __half w1s[64][64];     // [c_in][k_out]
    __shared__ __half w2s[64][64];     // [j_in][c_out]
    __shared__ float  dwks[576];
    __shared__ float  pb1s[64], pb2s[64], rdwbs[64], lss[64];
    int t = threadIdx.x;
    for (int i = t; i < 4096; i += 512) {
        w1s[i>>6][i&63] = __float2half(pw1T[i]);
        w2s[i>>6][i&63] = __float2half(pw2T[i]);
    }
    for (int i = t; i < 576; i += 512) dwks[i] = rdwk[i];
    if (t < 64) { pb1s[t]=pb1[t]; pb2s[t]=pb2[t]; rdwbs[t]=rdwb[t]; lss[t]=ls[t]; }

    int l = t & 127;
    int w = t >> 7;            // 0..3 (c0 wave-uniform)
    int c0 = w << 4;
    int p = blockIdx.x * 128 + l;
    int b  = p >> 14;
    int sp = p & (HWn - 1);
    int y = sp >> 7, x = sp & 127;
    int base = b * Cn * HWn + sp;

    int   yo[3] = { y > 0 ? -Wn : 0, 0, y < Hn-1 ? Wn : 0 };
    int   xo[3] = { x > 0 ? -1  : 0, 0, x < Wn-1 ? 1  : 0 };
    float myv[3] = { y > 0 ? 1.f : 0.f, 1.f, y < Hn-1 ? 1.f : 0.f };
    float mxv[3] = { x > 0 ? 1.f : 0.f, 1.f, x < Wn-1 ? 1.f : 0.f };
    float mm[9]; int oo[9];
#pragma unroll
    for (int dy = 0; dy < 3; dy++)
#pragma unroll
        for (int dx = 0; dx < 3; dx++) { mm[dy*3+dx] = myv[dy]*mxv[dx]; oo[dy*3+dx] = yo[dy]+xo[dx]; }
    __syncthreads();

    // phase 1: depthwise conv for this group's 16 channels
#pragma unroll
    for (int cc = 0; cc < 16; cc++) {
        int c = c0 + cc;
        int cb = base + c*HWn;
        float rv = rdwbs[c];
#pragma unroll
        for (int tt = 0; tt < 9; tt++)
            rv += (dwks[c*9 + tt] * mm[tt]) * __half2float(outp[cb + oo[tt]]);
        rv_s[c][l] = __float2half(rv);
    }
    __syncthreads();

    // phase 2: act[k] = lrelu(pb1[k] + sum_c pw1[k][c]*rv[c]) — LDS broadcast weights
    float acc[16];
#pragma unroll
    for (int kk = 0; kk < 16; kk++) acc[kk] = pb1s[c0 + kk];
#pragma unroll 4
    for (int c = 0; c < 64; c++) {
        float rv = __half2float(rv_s[c][l]);
        const __half2* wrow = (const __half2*)&w1s[c][c0];
#pragma unroll
        for (int q = 0; q < 8; q++) {
            float2 wf = __half22float2(wrow[q]);
            acc[2*q]   += wf.x * rv;
            acc[2*q+1] += wf.y * rv;
        }
    }
#pragma unroll
    for (int kk = 0; kk < 16; kk++) {
        float a = acc[kk];
        act_s[c0 + kk][l] = __float2half(a > 0.f ? a : 0.2f*a);
    }
    __syncthreads();

    // phase 3: out = outp + ls * (pb2 + pw2 @ act)
#pragma unroll
    for (int cc = 0; cc < 16; cc++) acc[cc] = pb2s[c0 + cc];
#pragma unroll 4
    for (int j = 0; j < 64; j++) {
        float a = __half2float(act_s[j][l]);
        const __half2* wrow = (const __half2*)&w2s[j][c0];
#pragma unroll
        for (int q = 0; q < 8; q++) {
            float2 wf = __half22float2(wrow[q]);
            acc[2*q]   += wf.x * a;
            acc[2*q+1] += wf.y * a;
        }
    }
#pragma unroll
    for (int cc = 0; cc < 16; cc++) {
        int c = c0 + cc;
        int cb = base + c*HWn;
        out[cb] = __half2float(outp[cb]) + lss[c] * acc[cc];
    }
}

extern "C" void kernel_launch(void* const* d_in, const int* in_sizes, int n_in,
                              void* d_out, int out_size, void* d_ws, size_t ws_size,
                              hipStream_t stream)
{
    (void)in_sizes; (void)n_in; (void)out_size; (void)ws_size;
    const float* force   = (const float*)d_in[0];
    const float* style   = (const float*)d_in[1];
    const float* illum   = (const float*)d_in[2];
    const float* h_w1    = (const float*)d_in[3];
    const float* h_b1    = (const float*)d_in[4];
    const float* h_w2    = (const float*)d_in[5];
    const float* h_b2    = (const float*)d_in[6];
    const float* h_w3    = (const float*)d_in[7];
    const float* h_b3    = (const float*)d_in[8];
    const float* dw_k    = (const float*)d_in[9];
    const float* pw_w    = (const float*)d_in[10];
    const float* r_dw_k  = (const float*)d_in[11];
    const float* r_dw_b  = (const float*)d_in[12];
    const float* r_pw1_w = (const float*)d_in[13];
    const float* r_pw1_b = (const float*)d_in[14];
    const float* r_pw2_w = (const float*)d_in[15];
    const float* r_pw2_b = (const float*)d_in[16];
    const float* lscale  = (const float*)d_in[17];

    float* out  = (float*)d_out;              // holds GB (half2) until refine overwrites
    float* Xf32 = out + (size_t)NTOT;         // final x fp32
    float* Vf32 = out + 2*(size_t)NTOT;       // final v fp32
    __half2* GB = (__half2*)out;

    char* w = (char*)d_ws;
    __half2* AB = (__half2*)w; w += (size_t)NTOT*4;
    __half*  F  = (__half*)w;  w += (size_t)NTOT*2;
    __half*  XA = (__half*)w;  w += (size_t)NTOT*2;
    __half*  XB = (__half*)w;  w += (size_t)NTOT*2;
    __half*  Vh = (__half*)w;  w += (size_t)NTOT*2;
    float* w1T  = (float*)w;
    float* c1   = w1T + 2048;
    float* pwT  = c1 + 32;
    float* pw1T = pwT + 4096;
    float* pw2T = pw1T + 4096;
    float* mu   = pw2T + 4096;
    float* rs   = mu + 512;
    __half* outp = (__half*)AB;               // AB dead after last osc step

    fuseF0<<<NTOT/1024, 256, 0, stream>>>((const float4*)force, (const float4*)illum,
                                          F, XA, Vh);
    prep<<<1, 256, 0, stream>>>(style, h_w1, h_b1, pw_w, r_pw1_w, r_pw2_w,
                                w1T, c1, pwT, pw1T, pw2T);
    hyper2<<<dim3(NPIX/256, 2), 256, 0, stream>>>(F, w1T, c1, h_w2, h_b2, h_w3, h_b3,
                                                  AB, GB);
    for (int s = 1; s <= 8; s++) {
        const __half* xin = (s & 1) ? XA : XB;
        __half*      xout = (s & 1) ? XB : XA;
        osc2<false><<<dim3(NPIX/512, 4), 256, 0, stream>>>(xin, xout, Vh, F, AB,
                                                           dw_k, pwT, nullptr, nullptr);
    }
    // step 9 (odd): reads XA, writes fp32 x,v directly to d_out
    osc2<true><<<dim3(NPIX/512, 4), 256, 0, stream>>>(XA, XB, Vh, F, AB,
                                                      dw_k, pwT, Xf32, Vf32);
    inorm_stats<<<Bn*Cn, 256, 0, stream>>>(F, Xf32, mu, rs);
    modulate<<<NTOT/1024, 256, 0, stream>>>(F, (const float4*)Xf32,
                                            (const uint4*)GB, mu, rs, outp);
    refine<<<NPIX/128, 512, 0, stream>>>(outp, r_dw_k, r_dw_b, pw1T, r_pw1_b,
                                         pw2T, r_pw2_b, lscale, out);
}

// Round 8
// 565.792 us; speedup vs baseline: 1.2802x; 1.2802x over previous
//
#include <hip/hip_runtime.h>
#include <hip/hip_fp16.h>

#define Hn 128
#define Wn 128
#define HWn 16384
#define Cn 64
#define Bn 8
#define NTOT (Bn*Cn*HWn)   /* 8388608 */
#define NPIX (Bn*HWn)      /* 131072  */
#define DTc 0.3f
#define EPSc 1e-5f

__device__ __forceinline__ float sigm(float t){ return 1.0f/(1.0f+__expf(-t)); }

// ---------------- F = force + 0.2*illum (fp16) + fused oscillator step 0 ----------------
// x0=v0=0  =>  accel0 = F, v1 = 0.3*F, x1 = 0.09*F
__global__ void fuseF0(const float4* __restrict__ force, const float4* __restrict__ illum,
                       __half* __restrict__ F, __half* __restrict__ XA, __half* __restrict__ V)
{
    int i = blockIdx.x * blockDim.x + threadIdx.x;      // NTOT/4 threads
    float4 f = force[i], il = illum[i];
    float a0 = f.x + 0.2f*il.x, a1 = f.y + 0.2f*il.y;
    float a2 = f.z + 0.2f*il.z, a3 = f.w + 0.2f*il.w;
    uint2 pf, px, pv;
    __half2 h;
    h = __floats2half2_rn(a0, a1);            pf.x = *(unsigned int*)&h;
    h = __floats2half2_rn(a2, a3);            pf.y = *(unsigned int*)&h;
    h = __floats2half2_rn(0.09f*a0, 0.09f*a1); px.x = *(unsigned int*)&h;
    h = __floats2half2_rn(0.09f*a2, 0.09f*a3); px.y = *(unsigned int*)&h;
    h = __floats2half2_rn(0.3f*a0, 0.3f*a1);   pv.x = *(unsigned int*)&h;
    h = __floats2half2_rn(0.3f*a2, 0.3f*a3);   pv.y = *(unsigned int*)&h;
    *reinterpret_cast<uint2*>(F  + 4*(size_t)i) = pf;
    *reinterpret_cast<uint2*>(XA + 4*(size_t)i) = px;
    *reinterpret_cast<uint2*>(V  + 4*(size_t)i) = pv;
}

// ---------------- prep: style constant + weight transposes ----------------
__global__ void prep(const float* __restrict__ style, const float* __restrict__ w1,
                     const float* __restrict__ b1, const float* __restrict__ pw,
                     const float* __restrict__ pw1, const float* __restrict__ pw2,
                     float* __restrict__ w1T, float* __restrict__ c1,
                     float* __restrict__ pwT, float* __restrict__ pw1T,
                     float* __restrict__ pw2T)
{
    int t = threadIdx.x;
    if (t < 32) {
        float s = b1[t];
        for (int k = 0; k < 64; k++) s += w1[t*128 + 64 + k] * style[k];
        c1[t] = s;
    }
    for (int i = t; i < 2048; i += 256) { int c = i >> 5, j = i & 31; w1T[i] = w1[j*128 + c]; }
    for (int i = t; i < 4096; i += 256) {
        int c = i >> 6, k = i & 63;
        pwT[i]  = pw[k*64 + c];
        pw1T[i] = pw1[k*64 + c];
        pw2T[i] = pw2[k*64 + c];
    }
}

// ---------------- hyper encoder, 2-way split: y=0 -> AB(half2), y=1 -> GB(half2) --------
__global__ void hyper2(const __half* __restrict__ F,
                       const float* __restrict__ w1T, const float* __restrict__ c1,
                       const float* __restrict__ w2, const float* __restrict__ b2,
                       const float* __restrict__ w3, const float* __restrict__ b3,
                       __half2* __restrict__ AB, __half2* __restrict__ GB)
{
    int p = blockIdx.x * blockDim.x + threadIdx.x;
    int b  = p >> 14;
    int sp = p & (HWn - 1);
    int base = b * Cn * HWn + sp;

    float u1[32];
#pragma unroll
    for (int j = 0; j < 32; j++) u1[j] = c1[j];
#pragma unroll 4
    for (int c = 0; c < 64; c++) {
        float fc = __half2float(F[base + c*HWn]);
        const float* __restrict__ wr = w1T + c*32;
#pragma unroll
        for (int j = 0; j < 32; j++) u1[j] += wr[j] * fc;
    }
#pragma unroll
    for (int j = 0; j < 32; j++) { float v = u1[j]; u1[j] = v > 0.f ? v : 0.2f*v; }

    float u2[32];
#pragma unroll
    for (int i = 0; i < 32; i++) {
        float s = b2[i];
#pragma unroll
        for (int j = 0; j < 32; j++) s += w2[i*32 + j] * u1[j];
        u2[i] = s > 0.f ? s : 0.2f*s;
    }

    if (blockIdx.y == 0) {
        for (int j = 0; j < 64; j++) {
            const float* __restrict__ r0 = w3 + j*32;
            const float* __restrict__ r1 = w3 + (64 + j)*32;
            float pwv = b3[j], pz = b3[64 + j];
#pragma unroll
            for (int i = 0; i < 32; i++) { pwv += r0[i]*u2[i]; pz += r1[i]*u2[i]; }
            float om = 2.0f * sigm(pwv);
            float ze = sigm(pz);
            AB[base + j*HWn] = __floats2half2_rn(2.0f * ze * om, om * om);
        }
    } else {
        for (int j = 0; j < 64; j++) {
            const float* __restrict__ r2 = w3 + (128 + j)*32;
            const float* __restrict__ r3 = w3 + (192 + j)*32;
            float pg = b3[128 + j], pb = b3[192 + j];
#pragma unroll
            for (int i = 0; i < 32; i++) { pg += r2[i]*u2[i]; pb += r3[i]*u2[i]; }
            GB[base + j*HWn] = __floats2half2_rn(2.0f * sigm(pg), tanhf(pb));
        }
    }
}

// ---------------- one symplectic-Euler oscillator step, 16-channel split, fp16 state ------
// (R5-proven structure: 1 px/thread, dim3(512,4) grid -> 32 waves/CU)
template <bool LAST>
__global__ void osc_step(const __half* __restrict__ Xin, __half* __restrict__ Xout,
                         __half* __restrict__ V, const __half* __restrict__ F,
                         const __half2* __restrict__ AB,
                         const float* __restrict__ dwk, const float* __restrict__ pwT,
                         float* __restrict__ Xf, float* __restrict__ Vf)
{
    int p = blockIdx.x * blockDim.x + threadIdx.x;
    int c0 = blockIdx.y << 4;                 // channel group start
    int b  = p >> 14;
    int sp = p & (HWn - 1);
    int y = sp >> 7, x = sp & 127;
    int base = b * Cn * HWn + sp;

    // pointwise coupling: acc[kk] = sum_c pw[c0+kk][c] * x[c]
    float acc[16];
#pragma unroll
    for (int k = 0; k < 16; k++) acc[k] = 0.f;
#pragma unroll 4
    for (int c = 0; c < 64; c++) {
        float xc = __half2float(Xin[base + c*HWn]);
        const float* __restrict__ wr = pwT + c*64 + c0;
#pragma unroll
        for (int k = 0; k < 16; k++) acc[k] += wr[k] * xc;
    }

    // 3x3 tap masks/offsets (zero 'SAME' padding)
    int   yo[3] = { y > 0 ? -Wn : 0, 0, y < Hn-1 ? Wn : 0 };
    int   xo[3] = { x > 0 ? -1  : 0, 0, x < Wn-1 ? 1  : 0 };
    float my[3] = { y > 0 ? 1.f : 0.f, 1.f, y < Hn-1 ? 1.f : 0.f };
    float mx[3] = { x > 0 ? 1.f : 0.f, 1.f, x < Wn-1 ? 1.f : 0.f };
    float mm[9]; int oo[9];
#pragma unroll
    for (int dy = 0; dy < 3; dy++)
#pragma unroll
        for (int dx = 0; dx < 3; dx++) { mm[dy*3+dx] = my[dy]*mx[dx]; oo[dy*3+dx] = yo[dy]+xo[dx]; }

#pragma unroll
    for (int cc = 0; cc < 16; cc++) {
        int c = c0 + cc;
        int cb = base + c*HWn;
        float tv[9];
#pragma unroll
        for (int t = 0; t < 9; t++) tv[t] = __half2float(Xin[cb + oo[t]]);
        float dws = 0.f;
#pragma unroll
        for (int t = 0; t < 9; t++) dws += (dwk[c*9 + t] * mm[t]) * tv[t];
        float xc = tv[4];
        float2 ab = __half22float2(AB[cb]);
        float vv = __half2float(V[cb]);
        float accel = __half2float(F[cb]) + acc[cc] + dws - ab.x * vv - ab.y * xc;
        vv += accel * DTc;
        float xn = xc + vv * DTc;
        if constexpr (!LAST) {
            V[cb] = __float2half(vv);
            Xout[cb] = __float2half(xn);
        } else {
            Xf[cb] = xn;
            Vf[cb] = vv;
        }
    }
}

// ---------------- instance norm stats ----------------
__global__ void inorm_stats(const __half* __restrict__ F, const float* __restrict__ X,
                            float* __restrict__ mu, float* __restrict__ rs)
{
    int bc = blockIdx.x;             // 0..511
    int base = bc * HWn;
    const __half2* __restrict__ F2 = (const __half2*)(F + base);
    const float4*  __restrict__ X4 = (const float4*)(X + base);
    float s = 0.f, s2 = 0.f;
    for (int i = threadIdx.x; i < HWn/4; i += blockDim.x) {
        float4 xv = X4[i];
        float2 f0 = __half22float2(F2[2*i]);
        float2 f1 = __half22float2(F2[2*i+1]);
        float v0 = f0.x + xv.x, v1 = f0.y + xv.y, v2 = f1.x + xv.z, v3 = f1.y + xv.w;
        s += (v0 + v1) + (v2 + v3);
        s2 += (v0*v0 + v1*v1) + (v2*v2 + v3*v3);
    }
#pragma unroll
    for (int o = 32; o > 0; o >>= 1) { s += __shfl_down(s, o); s2 += __shfl_down(s2, o); }
    __shared__ float sh[16];
    int w = threadIdx.x >> 6, l = threadIdx.x & 63;
    if (l == 0) { sh[w] = s; sh[8 + w] = s2; }
    __syncthreads();
    if (threadIdx.x == 0) {
        float S = 0.f, S2 = 0.f;
        for (int i = 0; i < 4; i++) { S += sh[i]; S2 += sh[8 + i]; }
        float m = S / (float)HWn;
        float var = S2 / (float)HWn - m*m;
        mu[bc] = m;
        rs[bc] = rsqrtf(var + EPSc);
    }
}

// ---------------- instance norm apply + style modulation -> out_pre (fp16) ----------------
__global__ void modulate(const __half* __restrict__ F, const float4* __restrict__ X4,
                         const uint4* __restrict__ GBu, const float* __restrict__ mu,
                         const float* __restrict__ rs, __half* __restrict__ outp)
{
    int e4 = blockIdx.x * blockDim.x + threadIdx.x;   // NTOT/4 threads
    int bc = e4 >> 12;                                // (e4*4) >> 14
    float m = mu[bc], r = rs[bc];
    uint2 fu = *reinterpret_cast<const uint2*>(F + 4*(size_t)e4);
    float2 f0 = __half22float2(*(__half2*)&fu.x);
    float2 f1 = __half22float2(*(__half2*)&fu.y);
    float4 xv = X4[e4];
    uint4 gb = GBu[e4];
    float2 g0 = __half22float2(*(__half2*)&gb.x);
    float2 g1 = __half22float2(*(__half2*)&gb.y);
    float2 g2 = __half22float2(*(__half2*)&gb.z);
    float2 g3 = __half22float2(*(__half2*)&gb.w);
    float o0 = g0.x * ((f0.x + xv.x - m) * r) + g0.y;
    float o1 = g1.x * ((f0.y + xv.y - m) * r) + g1.y;
    float o2 = g2.x * ((f1.x + xv.z - m) * r) + g2.y;
    float o3 = g3.x * ((f1.y + xv.w - m) * r) + g3.y;
    __half2 h01 = __floats2half2_rn(o0, o1);
    __half2 h23 = __floats2half2_rn(o2, o3);
    uint2 pack; pack.x = *(unsigned int*)&h01; pack.y = *(unsigned int*)&h23;
    *reinterpret_cast<uint2*>(outp + 4*(size_t)e4) = pack;
}

// ---------------- refine: LDS weights + packed fp16 hfma2 phases 2/3 ----------------
__global__ __launch_bounds__(512)
void refine(const __half* __restrict__ outp,
            const float* __restrict__ rdwk, const float* __restrict__ rdwb,
            const float* __restrict__ pw1T, const float* __restrict__ pb1,
            const float* __restrict__ pw2T, const float* __restrict__ pb2,
            const float* __restrict__ ls, float* __restrict__ out)
{
    __shared__ __half rv_s[64][128];
    __shared__ __half act_s[64][128];
    __shared__ __half w1s[64][64];     // [c_in][k_out]
    __shared__ __half w2s[64][64];     // [j_in][c_out]
    __shared__ float  dwks[576];
    __shared__ __half2 pb1h[32], pb2h[32];
    __shared__ float  rdwbs[64], lss[64];
    int t = threadIdx.x;
    for (int i = t; i < 4096; i += 512) {
        w1s[i>>6][i&63] = __float2half(pw1T[i]);
        w2s[i>>6][i&63] = __float2half(pw2T[i]);
    }
    for (int i = t; i < 576; i += 512) dwks[i] = rdwk[i];
    if (t < 64) { rdwbs[t]=rdwb[t]; lss[t]=ls[t]; }
    if (t < 32) {
        pb1h[t] = __floats2half2_rn(pb1[2*t], pb1[2*t+1]);
        pb2h[t] = __floats2half2_rn(pb2[2*t], pb2[2*t+1]);
    }

    int l = t & 127;
    int w = t >> 7;            // 0..3 (c0 wave-uniform)
    int c0 = w << 4;
    int p = blockIdx.x * 128 + l;
    int b  = p >> 14;
    int sp = p & (HWn - 1);
    int y = sp >> 7, x = sp & 127;
    int base = b * Cn * HWn + sp;

    int   yo[3] = { y > 0 ? -Wn : 0, 0, y < Hn-1 ? Wn : 0 };
    int   xo[3] = { x > 0 ? -1  : 0, 0, x < Wn-1 ? 1  : 0 };
    float myv[3] = { y > 0 ? 1.f : 0.f, 1.f, y < Hn-1 ? 1.f : 0.f };
    float mxv[3] = { x > 0 ? 1.f : 0.f, 1.f, x < Wn-1 ? 1.f : 0.f };
    float mm[9]; int oo[9];
#pragma unroll
    for (int dy = 0; dy < 3; dy++)
#pragma unroll
        for (int dx = 0; dx < 3; dx++) { mm[dy*3+dx] = myv[dy]*mxv[dx]; oo[dy*3+dx] = yo[dy]+xo[dx]; }
    __syncthreads();

    // phase 1: depthwise conv for this group's 16 channels
#pragma unroll
    for (int cc = 0; cc < 16; cc++) {
        int c = c0 + cc;
        int cb = base + c*HWn;
        float rv = rdwbs[c];
#pragma unroll
        for (int tt = 0; tt < 9; tt++)
            rv += (dwks[c*9 + tt] * mm[tt]) * __half2float(outp[cb + oo[tt]]);
        rv_s[c][l] = __float2half(rv);
    }
    __syncthreads();

    // phase 2: act[k] = lrelu(pb1[k] + sum_c pw1[k][c]*rv[c]) — packed hfma2
    __half2 acc2[8];
#pragma unroll
    for (int q = 0; q < 8; q++) acc2[q] = pb1h[(c0 >> 1) + q];
#pragma unroll 4
    for (int c = 0; c < 64; c++) {
        __half2 rvh = __half2half2(rv_s[c][l]);
        const __half2* wrow = (const __half2*)&w1s[c][c0];
#pragma unroll
        for (int q = 0; q < 8; q++) acc2[q] = __hfma2(wrow[q], rvh, acc2[q]);
    }
#pragma unroll
    for (int q = 0; q < 8; q++) {
        float2 a = __half22float2(acc2[q]);
        float a0 = a.x > 0.f ? a.x : 0.2f*a.x;
        float a1 = a.y > 0.f ? a.y : 0.2f*a.y;
        act_s[c0 + 2*q][l]     = __float2half(a0);
        act_s[c0 + 2*q + 1][l] = __float2half(a1);
    }
    __syncthreads();

    // phase 3: out = outp + ls * (pb2 + pw2 @ act) — packed hfma2
#pragma unroll
    for (int q = 0; q < 8; q++) acc2[q] = pb2h[(c0 >> 1) + q];
#pragma unroll 4
    for (int j = 0; j < 64; j++) {
        __half2 ah = __half2half2(act_s[j][l]);
        const __half2* wrow = (const __half2*)&w2s[j][c0];
#pragma unroll
        for (int q = 0; q < 8; q++) acc2[q] = __hfma2(wrow[q], ah, acc2[q]);
    }
#pragma unroll
    for (int q = 0; q < 8; q++) {
        float2 r = __half22float2(acc2[q]);
        int ca = c0 + 2*q, cb2 = c0 + 2*q + 1;
        int ba = base + ca*HWn, bb = base + cb2*HWn;
        out[ba] = __half2float(outp[ba]) + lss[ca] * r.x;
        out[bb] = __half2float(outp[bb]) + lss[cb2] * r.y;
    }
}

extern "C" void kernel_launch(void* const* d_in, const int* in_sizes, int n_in,
                              void* d_out, int out_size, void* d_ws, size_t ws_size,
                              hipStream_t stream)
{
    (void)in_sizes; (void)n_in; (void)out_size; (void)ws_size;
    const float* force   = (const float*)d_in[0];
    const float* style   = (const float*)d_in[1];
    const float* illum   = (const float*)d_in[2];
    const float* h_w1    = (const float*)d_in[3];
    const float* h_b1    = (const float*)d_in[4];
    const float* h_w2    = (const float*)d_in[5];
    const float* h_b2    = (const float*)d_in[6];
    const float* h_w3    = (const float*)d_in[7];
    const float* h_b3    = (const float*)d_in[8];
    const float* dw_k    = (const float*)d_in[9];
    const float* pw_w    = (const float*)d_in[10];
    const float* r_dw_k  = (const float*)d_in[11];
    const float* r_dw_b  = (const float*)d_in[12];
    const float* r_pw1_w = (const float*)d_in[13];
    const float* r_pw1_b = (const float*)d_in[14];
    const float* r_pw2_w = (const float*)d_in[15];
    const float* r_pw2_b = (const float*)d_in[16];
    const float* lscale  = (const float*)d_in[17];

    float* out  = (float*)d_out;              // holds GB (half2) until refine overwrites
    float* Xf32 = out + (size_t)NTOT;         // final x fp32
    float* Vf32 = out + 2*(size_t)NTOT;       // final v fp32
    __half2* GB = (__half2*)out;

    char* w = (char*)d_ws;
    __half2* AB = (__half2*)w; w += (size_t)NTOT*4;
    __half*  F  = (__half*)w;  w += (size_t)NTOT*2;
    __half*  XA = (__half*)w;  w += (size_t)NTOT*2;
    __half*  XB = (__half*)w;  w += (size_t)NTOT*2;
    __half*  Vh = (__half*)w;  w += (size_t)NTOT*2;
    float* w1T  = (float*)w;
    float* c1   = w1T + 2048;
    float* pwT  = c1 + 32;
    float* pw1T = pwT + 4096;
    float* pw2T = pw1T + 4096;
    float* mu   = pw2T + 4096;
    float* rs   = mu + 512;
    __half* outp = (__half*)AB;               // AB dead after last osc step

    fuseF0<<<NTOT/1024, 256, 0, stream>>>((const float4*)force, (const float4*)illum,
                                          F, XA, Vh);
    prep<<<1, 256, 0, stream>>>(style, h_w1, h_b1, pw_w, r_pw1_w, r_pw2_w,
                                w1T, c1, pwT, pw1T, pw2T);
    hyper2<<<dim3(NPIX/256, 2), 256, 0, stream>>>(F, w1T, c1, h_w2, h_b2, h_w3, h_b3,
                                                  AB, GB);
    for (int s = 1; s <= 8; s++) {
        const __half* xin = (s & 1) ? XA : XB;
        __half*      xout = (s & 1) ? XB : XA;
        osc_step<false><<<dim3(NPIX/256, 4), 256, 0, stream>>>(xin, xout, Vh, F, AB,
                                                               dw_k, pwT, nullptr, nullptr);
    }
    // step 9 (odd): reads XA, writes fp32 x,v directly to d_out
    osc_step<true><<<dim3(NPIX/256, 4), 256, 0, stream>>>(XA, XB, Vh, F, AB,
                                                          dw_k, pwT, Xf32, Vf32);
    inorm_stats<<<Bn*Cn, 256, 0, stream>>>(F, Xf32, mu, rs);
    modulate<<<NTOT/1024, 256, 0, stream>>>(F, (const float4*)Xf32,
                                            (const uint4*)GB, mu, rs, outp);
    refine<<<NPIX/128, 512, 0, stream>>>(outp, r_dw_k, r_dw_b, pw1T, r_pw1_b,
                                         pw2T, r_pw2_b, lscale, out);
}